// Round 6
// baseline (239.918 us; speedup 1.0000x reference)
//
#include <hip/hip_runtime.h>
#include <hip/hip_bf16.h>

#define CDIM   1024
#define NHEADS 16
#define DHEAD  64
#define BATCH  4
#define TSEQ   2048
#define MROWS  (BATCH * TSEQ)
#define QSTR   3072                /* fused qkv row stride */
#define NEG_BIG (-1e30f)
#define MASKVAL (-3.0e38f)
#define SCALE_L2E 0.18033688011f   /* 0.125 * log2(e) */
#define DEFER_TH 11.5416f          /* 8 nats in log2 units */

typedef __attribute__((ext_vector_type(8)))  short bf16x8;
typedef __attribute__((ext_vector_type(4)))  float f32x4;
typedef __attribute__((ext_vector_type(16))) float f32x16;

__device__ __forceinline__ unsigned short f2bf(float f) {
    __hip_bfloat16 h = __float2bfloat16(f);
    return *reinterpret_cast<unsigned short*>(&h);
}
__device__ __forceinline__ unsigned int pk2(float a, float b) {
    return (unsigned)f2bf(a) | ((unsigned)f2bf(b) << 16);
}
__device__ __forceinline__ float ex2(float x) {   // raw v_exp_f32 (exp2)
    float r; asm("v_exp_f32 %0, %1" : "=v"(r) : "v"(x)); return r;
}

// ---------------- x: fp32 -> bf16 (8 elems/thread) --------------------------
__global__ __launch_bounds__(256)
void cvt_x_kernel(const float* __restrict__ in, unsigned short* __restrict__ out)
{
    size_t i = (size_t)blockIdx.x * 256 + threadIdx.x;
    const float4* p = reinterpret_cast<const float4*>(in) + i * 2;
    float4 a = p[0], b = p[1];
    uint4 o;
    o.x = (unsigned)f2bf(a.x) | ((unsigned)f2bf(a.y) << 16);
    o.y = (unsigned)f2bf(a.z) | ((unsigned)f2bf(a.w) << 16);
    o.z = (unsigned)f2bf(b.x) | ((unsigned)f2bf(b.y) << 16);
    o.w = (unsigned)f2bf(b.z) | ((unsigned)f2bf(b.w) << 16);
    *reinterpret_cast<uint4*>(out + i * 8) = o;
}

// ---------------- W[K][N] fp32 -> W^T[N][K] bf16 (32x32 LDS tiles) ----------
__global__ __launch_bounds__(256)
void wt_kernel(const float* __restrict__ W0, const float* __restrict__ W1,
               const float* __restrict__ W2, const float* __restrict__ W3,
               unsigned short* __restrict__ T0, unsigned short* __restrict__ T1,
               unsigned short* __restrict__ T2, unsigned short* __restrict__ T3)
{
    const float* W; unsigned short* T;
    switch (blockIdx.z) {
        case 0:  W = W0; T = T0; break;
        case 1:  W = W1; T = T1; break;
        case 2:  W = W2; T = T2; break;
        default: W = W3; T = T3; break;
    }
    __shared__ float tile[32][33];
    const int t = threadIdx.x;
    const int r = t >> 3;
    const int c4 = (t & 7) * 4;
    const int n0 = blockIdx.x * 32, k0 = blockIdx.y * 32;
    float4 v = *reinterpret_cast<const float4*>(&W[(size_t)(k0 + r) * CDIM + n0 + c4]);
    tile[r][c4 + 0] = v.x; tile[r][c4 + 1] = v.y;
    tile[r][c4 + 2] = v.z; tile[r][c4 + 3] = v.w;
    __syncthreads();
    uint2 o;
    o.x = (unsigned)f2bf(tile[c4 + 0][r]) | ((unsigned)f2bf(tile[c4 + 1][r]) << 16);
    o.y = (unsigned)f2bf(tile[c4 + 2][r]) | ((unsigned)f2bf(tile[c4 + 3][r]) << 16);
    *reinterpret_cast<uint2*>(&T[(size_t)(n0 + r) * CDIM + k0 + c4]) = o;
}

// ---------------- bias concat [bq|bk|bv] ------------------------------------
__global__ __launch_bounds__(256)
void pack_bias(const float* __restrict__ bq, const float* __restrict__ bk,
               const float* __restrict__ bv, float* __restrict__ o)
{
    int i = blockIdx.x * 256 + threadIdx.x;   // 0..3071
    float v = (i < 1024) ? bq[i] : (i < 2048 ? bk[i - 1024] : bv[i - 2048]);
    o[i] = v;
}

// ---------------- m97-structure GEMM: C = A @ BT^T + bias, glds staging -----
template<int OUTMODE>
__global__ __launch_bounds__(256)
void gemm_glds(const unsigned short* __restrict__ A,
               const unsigned short* __restrict__ BT,
               const float* __restrict__ bias,
               void* __restrict__ Cout, int M, int N, int K, int nScaled)
{
    __shared__ __align__(16) unsigned short As[128 * 32];
    __shared__ __align__(16) unsigned short Bs[128 * 32];
    const int tid = threadIdx.x;
    const int nbn = N >> 7;
    const int bid = blockIdx.x;
    const int wg  = (bid & 7) * ((int)gridDim.x >> 3) + (bid >> 3);  // XCD swizzle
    const int n0  = (wg % nbn) * 128;
    const int m0  = (wg / nbn) * 128;

    const int lane = tid & 63, w = tid >> 6;
    const int wr = w >> 1, wc = w & 1;
    const int lj = lane & 15, lg = lane >> 4;
    const int rl = lane >> 2, sl = lane & 3;

    char* AsB = (char*)As;
    char* BsB = (char*)Bs;

    f32x4 acc[4][4];
    #pragma unroll
    for (int i = 0; i < 4; ++i)
        #pragma unroll
        for (int j = 0; j < 4; ++j) acc[i][j] = f32x4{0.f, 0.f, 0.f, 0.f};

    for (int k0 = 0; k0 < K; k0 += 32) {
        __syncthreads();
        #pragma unroll
        for (int t = 0; t < 2; ++t) {
            const int r = t * 64 + w * 16 + rl;
            const int g = sl ^ (r & 3);
            __builtin_amdgcn_global_load_lds(
                (const __attribute__((address_space(1))) void*)(A + (size_t)(m0 + r) * K + k0 + 8 * g),
                (__attribute__((address_space(3))) void*)(AsB + t * 4096 + w * 1024),
                16, 0, 0);
            __builtin_amdgcn_global_load_lds(
                (const __attribute__((address_space(1))) void*)(BT + (size_t)(n0 + r) * K + k0 + 8 * g),
                (__attribute__((address_space(3))) void*)(BsB + t * 4096 + w * 1024),
                16, 0, 0);
        }
        __syncthreads();
        bf16x8 af[4], bfr[4];
        #pragma unroll
        for (int i = 0; i < 4; ++i) {
            const int r = wr * 64 + i * 16 + lj;
            af[i] = *reinterpret_cast<const bf16x8*>(AsB + r * 64 + ((lg ^ (r & 3)) * 16));
        }
        #pragma unroll
        for (int j = 0; j < 4; ++j) {
            const int r = wc * 64 + j * 16 + lj;
            bfr[j] = *reinterpret_cast<const bf16x8*>(BsB + r * 64 + ((lg ^ (r & 3)) * 16));
        }
        #pragma unroll
        for (int i = 0; i < 4; ++i)
            #pragma unroll
            for (int j = 0; j < 4; ++j)
                acc[i][j] = __builtin_amdgcn_mfma_f32_16x16x32_bf16(af[i], bfr[j], acc[i][j], 0, 0, 0);
    }

    const float sc = (n0 < nScaled) ? SCALE_L2E : 1.0f;
    float bcol[4];
    #pragma unroll
    for (int j = 0; j < 4; ++j) bcol[j] = bias[n0 + wc * 64 + j * 16 + lj];

    #pragma unroll
    for (int i = 0; i < 4; ++i) {
        #pragma unroll
        for (int r4 = 0; r4 < 4; ++r4) {
            const int row = m0 + wr * 64 + i * 16 + lg * 4 + r4;
            #pragma unroll
            for (int j = 0; j < 4; ++j) {
                const int col = n0 + wc * 64 + j * 16 + lj;
                float v = (acc[i][j][r4] + bcol[j]) * sc;
                if (OUTMODE == 0)
                    reinterpret_cast<unsigned short*>(Cout)[(size_t)row * N + col] = f2bf(v);
                else
                    reinterpret_cast<float*>(Cout)[(size_t)row * N + col] = v;
            }
        }
    }
}

// ---------------- MFMA flash attention, T15 double-pipeline -----------------
// 512 blocks, 4 waves x 32 q-rows (128-row tile); balanced pair (p,15-p);
// XCD-grouped ids (R5-verified). LDS K/V double-buffered; per tile:
//   barrier / write buf[nxt] / barrier / load kt+2 / QK(kt+1)->sB (MFMA)
//   / FINISH(kt) on sA (softmax VALU + PV MFMA) -- QK overlaps softmax.
// ktend is always even => iter1's buf0 prologue write cannot race iter0's
// final FINISH (which reads buf1).

#define ZERO16(v) { _Pragma("unroll") for (int r_ = 0; r_ < 16; ++r_) (v)[r_] = 0.f; }

#define LOADT(T) do { \
    const unsigned short* kp_ = QKV + (rowbase + (T) * 64 + krow) * QSTR + hk + kcol8; \
    kr0 = *reinterpret_cast<const uint4*>(kp_); \
    kr1 = *reinterpret_cast<const uint4*>(kp_ + 32 * QSTR); \
    const unsigned short* vp_ = QKV + (rowbase + (T) * 64 + vk2) * QSTR + hv + vdg; \
    vr0 = *reinterpret_cast<const uint4*>(vp_); \
    vr1 = *reinterpret_cast<const uint4*>(vp_ + QSTR); \
} while (0)

#define STAGE_WRITE(b) do { \
    char* Kb_ = &ldsbuf[b][0]; \
    char* Vb_ = &ldsbuf[b][8192]; \
    *reinterpret_cast<uint4*>(Kb_ + krow * 128 + kswz) = kr0; \
    *reinterpret_cast<uint4*>(Kb_ + (krow + 32) * 128 + kswz) = kr1; \
    unsigned pe_, po_; \
    pe_ = __builtin_amdgcn_perm(vr1.x, vr0.x, 0x05040100u); \
    po_ = __builtin_amdgcn_perm(vr1.x, vr0.x, 0x07060302u); \
    *reinterpret_cast<unsigned*>(Vb_ + (vdg + 0) * 128 + (vkb ^ 0x00)) = pe_; \
    *reinterpret_cast<unsigned*>(Vb_ + (vdg + 1) * 128 + (vkb ^ 0x10)) = po_; \
    pe_ = __builtin_amdgcn_perm(vr1.y, vr0.y, 0x05040100u); \
    po_ = __builtin_amdgcn_perm(vr1.y, vr0.y, 0x07060302u); \
    *reinterpret_cast<unsigned*>(Vb_ + (vdg + 2) * 128 + (vkb ^ 0x20)) = pe_; \
    *reinterpret_cast<unsigned*>(Vb_ + (vdg + 3) * 128 + (vkb ^ 0x30)) = po_; \
    pe_ = __builtin_amdgcn_perm(vr1.z, vr0.z, 0x05040100u); \
    po_ = __builtin_amdgcn_perm(vr1.z, vr0.z, 0x07060302u); \
    *reinterpret_cast<unsigned*>(Vb_ + (vdg + 4) * 128 + (vkb ^ 0x40)) = pe_; \
    *reinterpret_cast<unsigned*>(Vb_ + (vdg + 5) * 128 + (vkb ^ 0x50)) = po_; \
    pe_ = __builtin_amdgcn_perm(vr1.w, vr0.w, 0x05040100u); \
    po_ = __builtin_amdgcn_perm(vr1.w, vr0.w, 0x07060302u); \
    *reinterpret_cast<unsigned*>(Vb_ + (vdg + 6) * 128 + (vkb ^ 0x60)) = pe_; \
    *reinterpret_cast<unsigned*>(Vb_ + (vdg + 7) * 128 + (vkb ^ 0x70)) = po_; \
} while (0)

#define QK_TILE(b, S0_, S1_) do { \
    char* Kb_ = &ldsbuf[b][0]; \
    __builtin_amdgcn_s_setprio(1); \
    _Pragma("unroll") \
    for (int s_ = 0; s_ < 4; ++s_) { \
        const int off_ = (s_ * 32 + hi * 16) ^ lqswz; \
        bf16x8 k0_ = *reinterpret_cast<const bf16x8*>(Kb_ + lq * 128 + off_); \
        bf16x8 k1_ = *reinterpret_cast<const bf16x8*>(Kb_ + (lq + 32) * 128 + off_); \
        S0_ = __builtin_amdgcn_mfma_f32_32x32x16_bf16(k0_, qf[s_], S0_, 0, 0, 0); \
        S1_ = __builtin_amdgcn_mfma_f32_32x32x16_bf16(k1_, qf[s_], S1_, 0, 0, 0); \
    } \
    __builtin_amdgcn_s_setprio(0); \
} while (0)

#define PV_STEP(m, T, rb, Vb_) { \
    unsigned int w01 = pk2(T[(rb)+0], T[(rb)+1]); \
    unsigned int w23 = pk2(T[(rb)+2], T[(rb)+3]); \
    unsigned int w45 = pk2(T[(rb)+4], T[(rb)+5]); \
    unsigned int w67 = pk2(T[(rb)+6], T[(rb)+7]); \
    asm("v_permlane32_swap_b32 %0, %1" : "+v"(w01), "+v"(w45)); \
    asm("v_permlane32_swap_b32 %0, %1" : "+v"(w23), "+v"(w67)); \
    union { unsigned int u[4]; bf16x8 v; } pa; \
    pa.u[0] = w01; pa.u[1] = w23; pa.u[2] = w45; pa.u[3] = w67; \
    const int voff = (32 * (m) + 16 * hi) ^ lqswz; \
    bf16x8 va = *reinterpret_cast<const bf16x8*>((Vb_) + lq * 128 + voff); \
    bf16x8 vb = *reinterpret_cast<const bf16x8*>((Vb_) + (lq + 32) * 128 + voff); \
    y0 = __builtin_amdgcn_mfma_f32_32x32x16_bf16(va, pa.v, y0, 0, 0, 0); \
    y1 = __builtin_amdgcn_mfma_f32_32x32x16_bf16(vb, pa.v, y1, 0, 0, 0); \
}

#define FINISH(S0_, S1_, b, ktv) do { \
    char* Vb_ = &ldsbuf[b][8192]; \
    const bool diag_ = ((ktv) * 64 + 63) > wq; \
    if (diag_) { \
        const int q_own_ = wq + lq; \
        _Pragma("unroll") \
        for (int r_ = 0; r_ < 16; ++r_) { \
            const int kl_ = (ktv) * 64 + (r_ & 3) + 8 * (r_ >> 2) + 4 * hi; \
            if (kl_ > q_own_) S0_[r_] = MASKVAL; \
            if (kl_ + 32 > q_own_) S1_[r_] = MASKVAL; \
        } \
    } \
    float t8_[8]; \
    _Pragma("unroll") \
    for (int r_ = 0; r_ < 8; ++r_) \
        t8_[r_] = fmaxf(fmaxf(S0_[r_], S0_[r_+8]), fmaxf(S1_[r_], S1_[r_+8])); \
    _Pragma("unroll") \
    for (int r_ = 0; r_ < 4; ++r_) t8_[r_] = fmaxf(t8_[r_], t8_[r_+4]); \
    float pm_ = fmaxf(fmaxf(t8_[0], t8_[1]), fmaxf(t8_[2], t8_[3])); \
    pm_ = fmaxf(pm_, __shfl_xor(pm_, 32)); \
    if (__any(pm_ > mrow + DEFER_TH)) { \
        const float mnew_ = fmaxf(mrow, pm_); \
        const float alpha_ = ex2(mrow - mnew_); \
        _Pragma("unroll") \
        for (int r_ = 0; r_ < 16; ++r_) { y0[r_] *= alpha_; y1[r_] *= alpha_; } \
        lrow *= alpha_; mrow = mnew_; \
    } \
    _Pragma("unroll") \
    for (int r_ = 0; r_ < 16; ++r_) { \
        S0_[r_] = ex2(S0_[r_] - mrow); \
        S1_[r_] = ex2(S1_[r_] - mrow); \
    } \
    float a8_[8]; \
    _Pragma("unroll") \
    for (int r_ = 0; r_ < 8; ++r_) a8_[r_] = (S0_[r_] + S0_[r_+8]) + (S1_[r_] + S1_[r_+8]); \
    _Pragma("unroll") \
    for (int r_ = 0; r_ < 4; ++r_) a8_[r_] += a8_[r_+4]; \
    float sum_ = (a8_[0] + a8_[1]) + (a8_[2] + a8_[3]); \
    sum_ += __shfl_xor(sum_, 32); \
    lrow += sum_; \
    __builtin_amdgcn_s_setprio(1); \
    PV_STEP(0, S0_, 0, Vb_) \
    PV_STEP(1, S0_, 8, Vb_) \
    PV_STEP(2, S1_, 0, Vb_) \
    PV_STEP(3, S1_, 8, Vb_) \
    __builtin_amdgcn_s_setprio(0); \
} while (0)

__global__ __launch_bounds__(256)
void attn_mfma5(const unsigned short* __restrict__ QKV, unsigned short* __restrict__ Yb)
{
    __shared__ __align__(16) char ldsbuf[2][16384];   // [buf][K 8KB | V^T 8KB]
    __shared__ __align__(16) char yscbuf[4][4608];    // per-wave epilogue

    const int tid = threadIdx.x, lane = tid & 63, wid = tid >> 6;
    const int lq = lane & 31, hi = lane >> 5;
    const int lqswz = (lq & 7) << 4;

    // XCD-grouped decomposition (R5): id%8 == hb%8 -> same (h,b) shares an XCD
    const int id  = blockIdx.x;
    const int kk  = id >> 3;
    const int hb  = (id & 7) + 8 * (kk >> 3);
    const int pair = kk & 7;
    const int h = hb & 15, bz = hb >> 4;

    const size_t rowbase = (size_t)bz * TSEQ;
    const int hq = h * DHEAD, hk = 1024 + h * DHEAD, hv = 2048 + h * DHEAD;

    // staging thread mapping (constant per thread)
    const int krow  = tid >> 3;                          // K rows krow, krow+32
    const int kcol8 = (tid & 7) * 8;
    const int kswz  = ((tid & 7) * 16) ^ ((krow & 7) << 4);
    const int vk2   = 2 * (tid & 31);                    // V key-pair
    const int vdg   = (tid >> 5) * 8;                    // V d-group
    const int vkb   = vk2 * 2;                           // byte offset of pair

    for (int iter = 0; iter < 2; ++iter) {
        const int qtile = iter ? (15 - pair) : pair;
        const int q0 = qtile * 128;
        const int wq = q0 + wid * 32;
        const int L  = (wq + 31) >> 6;        // last tile this wave computes
        const int ktend = 2 * qtile + 2;      // always even

        bf16x8 qf[4];                          // Q^T B-frags: d = 16s + 8hi + j
        {
            const unsigned short* qp = QKV + (rowbase + wq + lq) * QSTR + hq + hi * 8;
            #pragma unroll
            for (int s = 0; s < 4; ++s)
                qf[s] = *reinterpret_cast<const bf16x8*>(qp + s * 16);
        }
        f32x16 y0, y1;
        ZERO16(y0); ZERO16(y1);
        float mrow = NEG_BIG, lrow = 0.f;

        uint4 kr0, kr1, vr0, vr1;
        // prologue: stage tile 0, prefetch tile 1, QK(0)
        LOADT(0);
        STAGE_WRITE(0);
        if (ktend > 1) LOADT(1);
        __syncthreads();

        f32x16 sA0, sA1, sB0, sB1;
        ZERO16(sA0); ZERO16(sA1);
        QK_TILE(0, sA0, sA1);

        for (int kt = 0; kt < ktend; ++kt) {
            __syncthreads();                  // buf[(kt+1)&1] old readers done
            if (kt + 1 < ktend) STAGE_WRITE((kt + 1) & 1);
            __syncthreads();                  // publish
            if (kt + 2 < ktend) LOADT(kt + 2);

            const bool doNext = (kt + 1 < ktend) && (kt + 1 <= L);
            if (doNext) {
                ZERO16(sB0); ZERO16(sB1);
                QK_TILE((kt + 1) & 1, sB0, sB1);   // MFMA, overlaps FINISH VALU
            }
            if (kt <= L) FINISH(sA0, sA1, kt & 1, kt);
            if (doNext) { sA0 = sB0; sA1 = sB1; }
        }

        // ---- epilogue: normalize, transpose via per-wave LDS, coalesced store
        {
            const float inv = 1.f / lrow;
            char* ysb = &yscbuf[wid][0];
            #pragma unroll
            for (int t = 0; t < 8; ++t) {
                const int dl = ((2 * t) & 3) + 8 * (t >> 1) + 4 * hi;
                unsigned int wa = pk2(y0[2 * t] * inv, y0[2 * t + 1] * inv);
                unsigned int wb = pk2(y1[2 * t] * inv, y1[2 * t + 1] * inv);
                *reinterpret_cast<unsigned int*>(ysb + lq * 144 + dl * 2) = wa;
                *reinterpret_cast<unsigned int*>(ysb + lq * 144 + (dl + 32) * 2) = wb;
            }
            #pragma unroll
            for (int u = 0; u < 4; ++u) {
                const int rr = lane >> 1, ch = (lane & 1) + 2 * u;
                uint4 val = *reinterpret_cast<const uint4*>(ysb + rr * 144 + ch * 16);
                *reinterpret_cast<uint4*>(Yb + (rowbase + q0 + wid * 32 + rr) * CDIM + h * DHEAD + ch * 8) = val;
            }
        }
    }
}

// ---------------------------------------------------------------------------
extern "C" void kernel_launch(void* const* d_in, const int* in_sizes, int n_in,
                              void* d_out, int out_size, void* d_ws, size_t ws_size,
                              hipStream_t stream)
{
    const float* x  = (const float*)d_in[0];
    const float* Wk = (const float*)d_in[1];
    const float* bk = (const float*)d_in[2];
    const float* Wq = (const float*)d_in[3];
    const float* bq = (const float*)d_in[4];
    const float* Wv = (const float*)d_in[5];
    const float* bv = (const float*)d_in[6];
    const float* Wp = (const float*)d_in[7];
    const float* bp = (const float*)d_in[8];

    const size_t xe = (size_t)MROWS * CDIM;   // 8,388,608
    const size_t we = (size_t)CDIM * CDIM;    // 1,048,576
    unsigned short* xb    = (unsigned short*)d_ws;
    unsigned short* wqkvt = xb + xe;          // [3072][1024] = Wq^T|Wk^T|Wv^T
    unsigned short* wpt   = wqkvt + 3 * we;
    unsigned short* qkv   = wpt + we;         // [8192][3072] bf16
    unsigned short* ab    = qkv + (size_t)MROWS * QSTR;
    float*          bias3 = (float*)(ab + xe);

    cvt_x_kernel<<<(int)(xe / 8 / 256), 256, 0, stream>>>(x, xb);
    wt_kernel<<<dim3(32, 32, 4), 256, 0, stream>>>(
        Wq, Wk, Wv, Wp, wqkvt, wqkvt + we, wqkvt + 2 * we, wpt);
    pack_bias<<<12, 256, 0, stream>>>(bq, bk, bv, bias3);

    // fused QKV projection: [8192,1024] @ [1024,3072] + bias (q cols scaled)
    gemm_glds<0><<<24 * 64, 256, 0, stream>>>(xb, wqkvt, bias3, qkv,
                                              MROWS, QSTR, CDIM, 1024);

    attn_mfma5<<<512, 256, 0, stream>>>(qkv, ab);

    // output projection -> fp32
    gemm_glds<1><<<8 * 64, 256, 0, stream>>>(ab, wpt, bp, d_out,
                                             MROWS, CDIM, CDIM, 0);
}

// Round 7
// 183.736 us; speedup vs baseline: 1.3058x; 1.3058x over previous
//
#include <hip/hip_runtime.h>
#include <hip/hip_bf16.h>

#define CDIM   1024
#define NHEADS 16
#define DHEAD  64
#define BATCH  4
#define TSEQ   2048
#define MROWS  (BATCH * TSEQ)
#define QSTR   3072                /* fused qkv row stride */
#define NEG_BIG (-1e30f)
#define MASKVAL (-3.0e38f)
#define SCALE_L2E 0.18033688011f   /* 0.125 * log2(e) */
#define DEFER_TH 11.5416f          /* 8 nats in log2 units */

typedef __attribute__((ext_vector_type(8)))  short bf16x8;
typedef __attribute__((ext_vector_type(4)))  float f32x4;
typedef __attribute__((ext_vector_type(16))) float f32x16;

__device__ __forceinline__ unsigned short f2bf(float f) {
    __hip_bfloat16 h = __float2bfloat16(f);
    return *reinterpret_cast<unsigned short*>(&h);
}
__device__ __forceinline__ unsigned int pk2(float a, float b) {
    return (unsigned)f2bf(a) | ((unsigned)f2bf(b) << 16);
}
__device__ __forceinline__ unsigned int cvtpk(float a, float b) {
    unsigned r;
    asm("v_cvt_pk_bf16_f32 %0, %1, %2" : "=v"(r) : "v"(a), "v"(b));
    return r;   // lo = bf16(a), hi = bf16(b)
}
__device__ __forceinline__ float ex2(float x) {   // raw v_exp_f32 (exp2)
    float r; asm("v_exp_f32 %0, %1" : "=v"(r) : "v"(x)); return r;
}

// ---------------- x: fp32 -> bf16 (8 elems/thread) --------------------------
__global__ __launch_bounds__(256)
void cvt_x_kernel(const float* __restrict__ in, unsigned short* __restrict__ out)
{
    size_t i = (size_t)blockIdx.x * 256 + threadIdx.x;
    const float4* p = reinterpret_cast<const float4*>(in) + i * 2;
    float4 a = p[0], b = p[1];
    uint4 o;
    o.x = (unsigned)f2bf(a.x) | ((unsigned)f2bf(a.y) << 16);
    o.y = (unsigned)f2bf(a.z) | ((unsigned)f2bf(a.w) << 16);
    o.z = (unsigned)f2bf(b.x) | ((unsigned)f2bf(b.y) << 16);
    o.w = (unsigned)f2bf(b.z) | ((unsigned)f2bf(b.w) << 16);
    *reinterpret_cast<uint4*>(out + i * 8) = o;
}

// ---------------- W[K][N] fp32 -> W^T[N][K] bf16 (32x32 LDS tiles) ----------
__global__ __launch_bounds__(256)
void wt_kernel(const float* __restrict__ W0, const float* __restrict__ W1,
               const float* __restrict__ W2, const float* __restrict__ W3,
               unsigned short* __restrict__ T0, unsigned short* __restrict__ T1,
               unsigned short* __restrict__ T2, unsigned short* __restrict__ T3)
{
    const float* W; unsigned short* T;
    switch (blockIdx.z) {
        case 0:  W = W0; T = T0; break;
        case 1:  W = W1; T = T1; break;
        case 2:  W = W2; T = T2; break;
        default: W = W3; T = T3; break;
    }
    __shared__ float tile[32][33];
    const int t = threadIdx.x;
    const int r = t >> 3;
    const int c4 = (t & 7) * 4;
    const int n0 = blockIdx.x * 32, k0 = blockIdx.y * 32;
    float4 v = *reinterpret_cast<const float4*>(&W[(size_t)(k0 + r) * CDIM + n0 + c4]);
    tile[r][c4 + 0] = v.x; tile[r][c4 + 1] = v.y;
    tile[r][c4 + 2] = v.z; tile[r][c4 + 3] = v.w;
    __syncthreads();
    uint2 o;
    o.x = (unsigned)f2bf(tile[c4 + 0][r]) | ((unsigned)f2bf(tile[c4 + 1][r]) << 16);
    o.y = (unsigned)f2bf(tile[c4 + 2][r]) | ((unsigned)f2bf(tile[c4 + 3][r]) << 16);
    *reinterpret_cast<uint2*>(&T[(size_t)(n0 + r) * CDIM + k0 + c4]) = o;
}

// ---------------- bias concat [bq|bk|bv] ------------------------------------
__global__ __launch_bounds__(256)
void pack_bias(const float* __restrict__ bq, const float* __restrict__ bk,
               const float* __restrict__ bv, float* __restrict__ o)
{
    int i = blockIdx.x * 256 + threadIdx.x;   // 0..3071
    float v = (i < 1024) ? bq[i] : (i < 2048 ? bk[i - 1024] : bv[i - 2048]);
    o[i] = v;
}

// ---------------- m97-structure GEMM: C = A @ BT^T + bias, glds staging -----
template<int OUTMODE>
__global__ __launch_bounds__(256)
void gemm_glds(const unsigned short* __restrict__ A,
               const unsigned short* __restrict__ BT,
               const float* __restrict__ bias,
               void* __restrict__ Cout, int M, int N, int K, int nScaled)
{
    __shared__ __align__(16) unsigned short As[128 * 32];
    __shared__ __align__(16) unsigned short Bs[128 * 32];
    const int tid = threadIdx.x;
    const int nbn = N >> 7;
    const int bid = blockIdx.x;
    const int wg  = (bid & 7) * ((int)gridDim.x >> 3) + (bid >> 3);  // XCD swizzle
    const int n0  = (wg % nbn) * 128;
    const int m0  = (wg / nbn) * 128;

    const int lane = tid & 63, w = tid >> 6;
    const int wr = w >> 1, wc = w & 1;
    const int lj = lane & 15, lg = lane >> 4;
    const int rl = lane >> 2, sl = lane & 3;

    char* AsB = (char*)As;
    char* BsB = (char*)Bs;

    f32x4 acc[4][4];
    #pragma unroll
    for (int i = 0; i < 4; ++i)
        #pragma unroll
        for (int j = 0; j < 4; ++j) acc[i][j] = f32x4{0.f, 0.f, 0.f, 0.f};

    for (int k0 = 0; k0 < K; k0 += 32) {
        __syncthreads();
        #pragma unroll
        for (int t = 0; t < 2; ++t) {
            const int r = t * 64 + w * 16 + rl;
            const int g = sl ^ (r & 3);
            __builtin_amdgcn_global_load_lds(
                (const __attribute__((address_space(1))) void*)(A + (size_t)(m0 + r) * K + k0 + 8 * g),
                (__attribute__((address_space(3))) void*)(AsB + t * 4096 + w * 1024),
                16, 0, 0);
            __builtin_amdgcn_global_load_lds(
                (const __attribute__((address_space(1))) void*)(BT + (size_t)(n0 + r) * K + k0 + 8 * g),
                (__attribute__((address_space(3))) void*)(BsB + t * 4096 + w * 1024),
                16, 0, 0);
        }
        __syncthreads();
        bf16x8 af[4], bfr[4];
        #pragma unroll
        for (int i = 0; i < 4; ++i) {
            const int r = wr * 64 + i * 16 + lj;
            af[i] = *reinterpret_cast<const bf16x8*>(AsB + r * 64 + ((lg ^ (r & 3)) * 16));
        }
        #pragma unroll
        for (int j = 0; j < 4; ++j) {
            const int r = wc * 64 + j * 16 + lj;
            bfr[j] = *reinterpret_cast<const bf16x8*>(BsB + r * 64 + ((lg ^ (r & 3)) * 16));
        }
        #pragma unroll
        for (int i = 0; i < 4; ++i)
            #pragma unroll
            for (int j = 0; j < 4; ++j)
                acc[i][j] = __builtin_amdgcn_mfma_f32_16x16x32_bf16(af[i], bfr[j], acc[i][j], 0, 0, 0);
    }

    const float sc = (n0 < nScaled) ? SCALE_L2E : 1.0f;
    float bcol[4];
    #pragma unroll
    for (int j = 0; j < 4; ++j) bcol[j] = bias[n0 + wc * 64 + j * 16 + lj];

    #pragma unroll
    for (int i = 0; i < 4; ++i) {
        #pragma unroll
        for (int r4 = 0; r4 < 4; ++r4) {
            const int row = m0 + wr * 64 + i * 16 + lg * 4 + r4;
            #pragma unroll
            for (int j = 0; j < 4; ++j) {
                const int col = n0 + wc * 64 + j * 16 + lj;
                float v = (acc[i][j][r4] + bcol[j]) * sc;
                if (OUTMODE == 0)
                    reinterpret_cast<unsigned short*>(Cout)[(size_t)row * N + col] = f2bf(v);
                else
                    reinterpret_cast<float*>(Cout)[(size_t)row * N + col] = v;
            }
        }
    }
}

// ---------------- MFMA flash attention (R5 structure + VALU diet) -----------
// 512 blocks, 4 waves x 32 q-rows = 128-row q-tile; balanced pair (p, 15-p)
// sequentially (uniform 34 KV-iterations). XCD-grouped id mapping (R5).
// KV single-LDS-buffer, reg prefetch of kt+1 (R5-verified sync skeleton).
// VALU diet vs R5: cvt_pk P-pack, tree reductions, raw v_exp, v_perm V-pack.
#define PV_STEP(m, T, rb) { \
    unsigned int w01 = cvtpk(T[(rb)+0], T[(rb)+1]); \
    unsigned int w23 = cvtpk(T[(rb)+2], T[(rb)+3]); \
    unsigned int w45 = cvtpk(T[(rb)+4], T[(rb)+5]); \
    unsigned int w67 = cvtpk(T[(rb)+6], T[(rb)+7]); \
    asm("v_permlane32_swap_b32 %0, %1" : "+v"(w01), "+v"(w45)); \
    asm("v_permlane32_swap_b32 %0, %1" : "+v"(w23), "+v"(w67)); \
    union { unsigned int u[4]; bf16x8 v; } pa; \
    pa.u[0] = w01; pa.u[1] = w23; pa.u[2] = w45; pa.u[3] = w67; \
    const int voff = (32 * (m) + 16 * hi) ^ lqswz; \
    bf16x8 va = *reinterpret_cast<const bf16x8*>(VTB + lq * 128 + voff); \
    bf16x8 vb = *reinterpret_cast<const bf16x8*>(VTB + (lq + 32) * 128 + voff); \
    y0 = __builtin_amdgcn_mfma_f32_32x32x16_bf16(va, pa.v, y0, 0, 0, 0); \
    y1 = __builtin_amdgcn_mfma_f32_32x32x16_bf16(vb, pa.v, y1, 0, 0, 0); \
}

__global__ __launch_bounds__(256)
void attn_mfma6(const unsigned short* __restrict__ QKV, unsigned short* __restrict__ Yb)
{
    __shared__ unsigned short Ks[64 * 64];    // [key][d], swizzled
    __shared__ unsigned short VTs[64 * 64];   // [d][key], swizzled
    __shared__ unsigned short Ysc[4][32 * 72];// per-wave [q][d], 144B stride

    const int tid = threadIdx.x, lane = tid & 63, wid = tid >> 6;
    const int lq = lane & 31, hi = lane >> 5;
    const int lqswz = (lq & 7) << 4;

    // XCD-grouped decomposition: id%8 == hb%8 -> same (h,b) shares an XCD
    const int id  = blockIdx.x;
    const int kk  = id >> 3;
    const int hb  = (id & 7) + 8 * (kk >> 3);
    const int pair = kk & 7;
    const int h = hb & 15, bz = hb >> 4;

    const size_t rowbase = (size_t)bz * TSEQ;
    const int hq = h * DHEAD, hk = 1024 + h * DHEAD, hv = 2048 + h * DHEAD;
    char* KsB = (char*)Ks;
    char* VTB = (char*)VTs;

    // staging thread mapping (constant per thread)
    const int krow = tid >> 3;           // K rows krow, krow+32
    const int kswz = ((tid & 7) * 16) ^ ((krow & 7) << 4);
    const int vk2  = 2 * (tid & 31);     // V key-pair
    const int vdg  = (tid >> 5) * 8;     // V d-group
    const int vkb  = vk2 * 2;            // byte offset of pair

    for (int iter = 0; iter < 2; ++iter) {
        const int qtile = iter ? (15 - pair) : pair;
        const int q0 = qtile * 128;
        const int wq = q0 + wid * 32;

        bf16x8 qf[4];                            // Q^T B-frags: d = 16s + 8hi + j
        {
            const unsigned short* qp = QKV + (rowbase + wq + lq) * QSTR + hq + hi * 8;
            #pragma unroll
            for (int s = 0; s < 4; ++s)
                qf[s] = *reinterpret_cast<const bf16x8*>(qp + s * 16);
        }
        f32x16 y0, y1;                           // Y^T tiles: d 0..31 / 32..63
        #pragma unroll
        for (int r = 0; r < 16; ++r) { y0[r] = 0.f; y1[r] = 0.f; }
        float mrow = NEG_BIG, lrow = 0.f;

        const int ktend = 2 * qtile + 2;

        // prefetch tile 0 into registers
        uint4 kr0, kr1, vr0, vr1;
        {
            const unsigned short* kp = QKV + (rowbase + krow) * QSTR + hk + (tid & 7) * 8;
            kr0 = *reinterpret_cast<const uint4*>(kp);
            kr1 = *reinterpret_cast<const uint4*>(kp + 32 * QSTR);
            const unsigned short* vp = QKV + (rowbase + vk2) * QSTR + hv + vdg;
            vr0 = *reinterpret_cast<const uint4*>(vp);
            vr1 = *reinterpret_cast<const uint4*>(vp + QSTR);
        }

        for (int kt = 0; kt < ktend; ++kt) {
            __syncthreads();                     // previous tile's consumers done
            // ---- write prefetched regs -> LDS (K swizzled, V^T perm-packed)
            *reinterpret_cast<uint4*>(KsB + krow * 128 + kswz) = kr0;
            *reinterpret_cast<uint4*>(KsB + (krow + 32) * 128 + kswz) = kr1;
            {
                unsigned pe, po;
                pe = __builtin_amdgcn_perm(vr1.x, vr0.x, 0x05040100u);
                po = __builtin_amdgcn_perm(vr1.x, vr0.x, 0x07060302u);
                *reinterpret_cast<unsigned*>(VTB + (vdg + 0) * 128 + (vkb ^ 0x00)) = pe;
                *reinterpret_cast<unsigned*>(VTB + (vdg + 1) * 128 + (vkb ^ 0x10)) = po;
                pe = __builtin_amdgcn_perm(vr1.y, vr0.y, 0x05040100u);
                po = __builtin_amdgcn_perm(vr1.y, vr0.y, 0x07060302u);
                *reinterpret_cast<unsigned*>(VTB + (vdg + 2) * 128 + (vkb ^ 0x20)) = pe;
                *reinterpret_cast<unsigned*>(VTB + (vdg + 3) * 128 + (vkb ^ 0x30)) = po;
                pe = __builtin_amdgcn_perm(vr1.z, vr0.z, 0x05040100u);
                po = __builtin_amdgcn_perm(vr1.z, vr0.z, 0x07060302u);
                *reinterpret_cast<unsigned*>(VTB + (vdg + 4) * 128 + (vkb ^ 0x40)) = pe;
                *reinterpret_cast<unsigned*>(VTB + (vdg + 5) * 128 + (vkb ^ 0x50)) = po;
                pe = __builtin_amdgcn_perm(vr1.w, vr0.w, 0x05040100u);
                po = __builtin_amdgcn_perm(vr1.w, vr0.w, 0x07060302u);
                *reinterpret_cast<unsigned*>(VTB + (vdg + 6) * 128 + (vkb ^ 0x60)) = pe;
                *reinterpret_cast<unsigned*>(VTB + (vdg + 7) * 128 + (vkb ^ 0x70)) = po;
            }
            __syncthreads();                     // LDS tile ready

            // ---- issue next tile's global loads (latency hides under compute)
            if (kt + 1 < ktend) {
                const unsigned short* kp = QKV + (rowbase + (kt + 1) * 64 + krow) * QSTR + hk + (tid & 7) * 8;
                kr0 = *reinterpret_cast<const uint4*>(kp);
                kr1 = *reinterpret_cast<const uint4*>(kp + 32 * QSTR);
                const unsigned short* vp = QKV + (rowbase + (kt + 1) * 64 + vk2) * QSTR + hv + vdg;
                vr0 = *reinterpret_cast<const uint4*>(vp);
                vr1 = *reinterpret_cast<const uint4*>(vp + QSTR);
            }

            if (kt * 64 > wq + 31) continue;     // tile above diagonal for this wave

            // ---- S^T = K Q^T (8 mfma 32x32x16); scale pre-folded into Q
            f32x16 s0, s1;
            #pragma unroll
            for (int r = 0; r < 16; ++r) { s0[r] = 0.f; s1[r] = 0.f; }
            #pragma unroll
            for (int s = 0; s < 4; ++s) {
                const int off = (s * 32 + hi * 16) ^ lqswz;
                bf16x8 k0 = *reinterpret_cast<const bf16x8*>(KsB + lq * 128 + off);
                bf16x8 k1 = *reinterpret_cast<const bf16x8*>(KsB + (lq + 32) * 128 + off);
                s0 = __builtin_amdgcn_mfma_f32_32x32x16_bf16(k0, qf[s], s0, 0, 0, 0);
                s1 = __builtin_amdgcn_mfma_f32_32x32x16_bf16(k1, qf[s], s1, 0, 0, 0);
            }

            // ---- causal mask (diagonal tiles only)
            const bool diag = (kt * 64 + 63) > wq;
            if (diag) {
                const int q_own = wq + lq;
                #pragma unroll
                for (int r = 0; r < 16; ++r) {
                    const int kl = kt * 64 + (r & 3) + 8 * (r >> 2) + 4 * hi;
                    if (kl > q_own) s0[r] = MASKVAL;
                    if (kl + 32 > q_own) s1[r] = MASKVAL;
                }
            }

            // ---- tree row max + pair exchange
            float t8[8];
            #pragma unroll
            for (int r = 0; r < 8; ++r)
                t8[r] = fmaxf(fmaxf(s0[r], s0[r + 8]), fmaxf(s1[r], s1[r + 8]));
            #pragma unroll
            for (int r = 0; r < 4; ++r) t8[r] = fmaxf(t8[r], t8[r + 4]);
            float pm = fmaxf(fmaxf(t8[0], t8[1]), fmaxf(t8[2], t8[3]));
            pm = fmaxf(pm, __shfl_xor(pm, 32));

            // ---- defer-max rescale (T13)
            if (__any(pm > mrow + DEFER_TH)) {
                const float mnew = fmaxf(mrow, pm);
                const float alpha = ex2(mrow - mnew);
                #pragma unroll
                for (int r = 0; r < 16; ++r) { y0[r] *= alpha; y1[r] *= alpha; }
                lrow *= alpha;
                mrow = mnew;
            }
            // ---- exp2 + tree row sum
            #pragma unroll
            for (int r = 0; r < 16; ++r) {
                s0[r] = ex2(s0[r] - mrow);
                s1[r] = ex2(s1[r] - mrow);
            }
            float a8[8];
            #pragma unroll
            for (int r = 0; r < 8; ++r) a8[r] = (s0[r] + s0[r + 8]) + (s1[r] + s1[r + 8]);
            #pragma unroll
            for (int r = 0; r < 4; ++r) a8[r] += a8[r + 4];
            float sum = (a8[0] + a8[1]) + (a8[2] + a8[3]);
            sum += __shfl_xor(sum, 32);
            lrow += sum;

            // ---- Y^T += V^T P^T (8 mfma); P^T frags via cvt_pk+permlane32_swap
            PV_STEP(0, s0, 0)
            PV_STEP(1, s0, 8)
            PV_STEP(2, s1, 0)
            PV_STEP(3, s1, 8)
        }

        // ---- epilogue: normalize, transpose via per-wave LDS, coalesced store
        {
            const float inv = 1.f / lrow;
            char* ysb = (char*)&Ysc[wid][0];
            #pragma unroll
            for (int t = 0; t < 8; ++t) {
                const int dl = ((2 * t) & 3) + 8 * (t >> 1) + 4 * hi;
                unsigned int wa = cvtpk(y0[2 * t] * inv, y0[2 * t + 1] * inv);
                unsigned int wb = cvtpk(y1[2 * t] * inv, y1[2 * t + 1] * inv);
                *reinterpret_cast<unsigned int*>(ysb + lq * 144 + dl * 2) = wa;
                *reinterpret_cast<unsigned int*>(ysb + lq * 144 + (dl + 32) * 2) = wb;
            }
            #pragma unroll
            for (int u = 0; u < 4; ++u) {
                const int rr = lane >> 1, ch = (lane & 1) + 2 * u;
                uint4 val = *reinterpret_cast<const uint4*>(ysb + rr * 144 + ch * 16);
                *reinterpret_cast<uint4*>(Yb + (rowbase + q0 + wid * 32 + rr) * CDIM + h * DHEAD + ch * 8) = val;
            }
        }
    }
}

// ---------------------------------------------------------------------------
extern "C" void kernel_launch(void* const* d_in, const int* in_sizes, int n_in,
                              void* d_out, int out_size, void* d_ws, size_t ws_size,
                              hipStream_t stream)
{
    const float* x  = (const float*)d_in[0];
    const float* Wk = (const float*)d_in[1];
    const float* bk = (const float*)d_in[2];
    const float* Wq = (const float*)d_in[3];
    const float* bq = (const float*)d_in[4];
    const float* Wv = (const float*)d_in[5];
    const float* bv = (const float*)d_in[6];
    const float* Wp = (const float*)d_in[7];
    const float* bp = (const float*)d_in[8];

    const size_t xe = (size_t)MROWS * CDIM;   // 8,388,608
    const size_t we = (size_t)CDIM * CDIM;    // 1,048,576
    unsigned short* xb    = (unsigned short*)d_ws;
    unsigned short* wqkvt = xb + xe;          // [3072][1024] = Wq^T|Wk^T|Wv^T
    unsigned short* wpt   = wqkvt + 3 * we;
    unsigned short* qkv   = wpt + we;         // [8192][3072] bf16
    unsigned short* ab    = qkv + (size_t)MROWS * QSTR;
    float*          bias3 = (float*)(ab + xe);

    cvt_x_kernel<<<(int)(xe / 8 / 256), 256, 0, stream>>>(x, xb);
    wt_kernel<<<dim3(32, 32, 4), 256, 0, stream>>>(
        Wq, Wk, Wv, Wp, wqkvt, wqkvt + we, wqkvt + 2 * we, wpt);
    pack_bias<<<12, 256, 0, stream>>>(bq, bk, bv, bias3);

    // fused QKV projection: [8192,1024] @ [1024,3072] + bias (q cols scaled)
    gemm_glds<0><<<24 * 64, 256, 0, stream>>>(xb, wqkvt, bias3, qkv,
                                              MROWS, QSTR, CDIM, 1024);

    attn_mfma6<<<512, 256, 0, stream>>>(qkv, ab);

    // output projection -> fp32
    gemm_glds<1><<<8 * 64, 256, 0, stream>>>(ab, wpt, bp, d_out,
                                             MROWS, CDIM, CDIM, 0);
}